// Round 7
// baseline (148.430 us; speedup 1.0000x reference)
//
#include <hip/hip_runtime.h>
#include <hip/hip_bf16.h>

// PGExplainer edge-MLP:
//   logits[e] = relu(concat(emb[src], emb[dst]) @ W1 + b1) @ W2 + b2
// Restructured: A[n] = emb[n] @ W1[:64] + b1 ; B[n] = emb[n] @ W1[64:]
//   logits[e] = relu(A[src]+B[dst]) . W2 + b2
// AB[n*128 + j] bf16 (j<64 = A, j>=64 = B) in d_ws.
//
// R7: edge gathers were L3-bound (~40us, insensitive to unroll depth:
// 1.6M random 128B lines, AB > per-XCD L2). Fix = locality:
//  - class = (src&7, dst&7) -> 64 classes; counting-sort edges by class
//    (hist fused into precompute launch; scatter kernel; int4 records).
//  - compute kernel pins class row i to XCD i (blockIdx%8), walks j in
//    order: per-XCD working set = A-shard i + B-shard j = 1.6MB < 4MiB L2.
// Precompute = R3 bare version (best measured partner, 102.7 total).

typedef __attribute__((ext_vector_type(8))) short bf16x8;
typedef __attribute__((ext_vector_type(4))) float f32x4;

#define PRE_BLOCKS  256
#define HIST_BLOCKS 1024
#define SCAT_BLOCKS 1024
#define MLP_BLOCKS  2048

__device__ __forceinline__ unsigned short f2bf(float f) {
    union { float f; unsigned int i; } v;
    v.f = f;
    unsigned int r = v.i + 0x7fffu + ((v.i >> 16) & 1u);  // RNE
    return (unsigned short)(r >> 16);
}

template <int N>
__device__ __forceinline__ float dpp_shr(float x) {
    return __int_as_float(__builtin_amdgcn_update_dpp(
        0, __float_as_int(x), 0x110 | N, 0xf, 0xf, true));
}

// relu(A+B).W2 partial over this lane's 8 hidden units, then 8-lane DPP
// reduce; sum lands at sub==7.
__device__ __forceinline__ float edge_dot(const uint4 ua, const uint4 ub,
                                          const float* __restrict__ w2v) {
    float p = 0.f;
    const unsigned int au[4] = {ua.x, ua.y, ua.z, ua.w};
    const unsigned int bu[4] = {ub.x, ub.y, ub.z, ub.w};
#pragma unroll
    for (int i = 0; i < 4; ++i) {
        const float alo = __int_as_float((int)(au[i] << 16));
        const float ahi = __int_as_float((int)(au[i] & 0xffff0000u));
        const float blo = __int_as_float((int)(bu[i] << 16));
        const float bhi = __int_as_float((int)(bu[i] & 0xffff0000u));
        p = fmaf(fmaxf(alo + blo, 0.f), w2v[2 * i], p);
        p = fmaf(fmaxf(ahi + bhi, 0.f), w2v[2 * i + 1], p);
    }
    p += dpp_shr<1>(p);
    p += dpp_shr<2>(p);
    p += dpp_shr<4>(p);
    return p;
}

// ---------------- fused: precompute AB (blocks < PRE_BLOCKS) + class
// histogram (remaining blocks). Independent workloads, overlapped. -------
__global__ __launch_bounds__(256) void pre_and_hist(
    const float* __restrict__ emb, const float* __restrict__ W1,
    const float* __restrict__ b1, unsigned short* __restrict__ AB,
    int nNodes, const int* __restrict__ ei, int nEdges,
    unsigned int* __restrict__ hist)
{
    __shared__ unsigned int h[64];
    if (blockIdx.x >= PRE_BLOCKS) {
        // ---- histogram body ----
        const int b = blockIdx.x - PRE_BLOCKS;
        if (threadIdx.x < 64) h[threadIdx.x] = 0;
        __syncthreads();
        for (int e = b * 256 + threadIdx.x; e < nEdges; e += HIST_BLOCKS * 256) {
            const int s = ei[e], d = ei[nEdges + e];
            atomicAdd(&h[((s & 7) << 3) | (d & 7)], 1u);
        }
        __syncthreads();
        if (threadIdx.x < 64) atomicAdd(&hist[threadIdx.x], h[threadIdx.x]);
        return;
    }

    // ---- precompute body (R3 bare MFMA version) ----
    // Frag layouts (mfma_f32_16x16x32_bf16):
    //  A: row=lane&15, k=(lane>>4)*8+i ; B: col=lane&15, same k
    //  D: col=lane&15, row=(lane>>4)*4+reg   [verified m89]
    const int lane = threadIdx.x & 63;
    const int waveId = blockIdx.x * 4 + (threadIdx.x >> 6);
    const int totalWaves = PRE_BLOCKS * 4;
    const int c  = lane & 15;
    const int kb = lane >> 4;

    bf16x8 wfrag[8][2];
    float bias[8];
#pragma unroll
    for (int nt = 0; nt < 8; ++nt) {
        const int jp = nt * 16 + c;                       // output col 0..127
        const float* wcol = (jp < 64) ? (W1 + jp) : (W1 + 64 * 64 + (jp - 64));
        bias[nt] = (jp < 64) ? b1[jp] : 0.f;
#pragma unroll
        for (int kk = 0; kk < 2; ++kk)
#pragma unroll
            for (int i = 0; i < 8; ++i) {
                const int k = kk * 32 + kb * 8 + i;
                wfrag[nt][kk][i] = (short)f2bf(wcol[(size_t)k * 64]);
            }
    }

    for (int n0 = waveId * 16; n0 < nNodes; n0 += totalWaves * 16) {
        const int arow = n0 + c;
        const float* erow = emb + (size_t)((arow < nNodes) ? arow : (nNodes - 1)) * 64 + kb * 8;
        bf16x8 afrag[2];
#pragma unroll
        for (int kk = 0; kk < 2; ++kk) {
            const float4 f0 = *reinterpret_cast<const float4*>(erow + kk * 32);
            const float4 f1 = *reinterpret_cast<const float4*>(erow + kk * 32 + 4);
            afrag[kk][0] = (short)f2bf(f0.x); afrag[kk][1] = (short)f2bf(f0.y);
            afrag[kk][2] = (short)f2bf(f0.z); afrag[kk][3] = (short)f2bf(f0.w);
            afrag[kk][4] = (short)f2bf(f1.x); afrag[kk][5] = (short)f2bf(f1.y);
            afrag[kk][6] = (short)f2bf(f1.z); afrag[kk][7] = (short)f2bf(f1.w);
        }

        f32x4 acc[8];
#pragma unroll
        for (int nt = 0; nt < 8; ++nt) {
            acc[nt][0] = bias[nt]; acc[nt][1] = bias[nt];
            acc[nt][2] = bias[nt]; acc[nt][3] = bias[nt];
        }
#pragma unroll
        for (int kk = 0; kk < 2; ++kk)
#pragma unroll
            for (int nt = 0; nt < 8; ++nt)
                acc[nt] = __builtin_amdgcn_mfma_f32_16x16x32_bf16(
                    afrag[kk], wfrag[nt][kk], acc[nt], 0, 0, 0);

        if (n0 + 16 <= nNodes) {
#pragma unroll
            for (int nt = 0; nt < 8; ++nt) {
                const int jp = nt * 16 + c;
#pragma unroll
                for (int r = 0; r < 4; ++r)
                    AB[(size_t)(n0 + kb * 4 + r) * 128 + jp] = f2bf(acc[nt][r]);
            }
        } else {
#pragma unroll
            for (int nt = 0; nt < 8; ++nt) {
                const int jp = nt * 16 + c;
#pragma unroll
                for (int r = 0; r < 4; ++r) {
                    const int node = n0 + kb * 4 + r;
                    if (node < nNodes) AB[(size_t)node * 128 + jp] = f2bf(acc[nt][r]);
                }
            }
        }
    }
}

// ---------------- scatter: counting-sort edges into class-ordered records --
__global__ __launch_bounds__(256) void edge_scatter(
    const int* __restrict__ ei, int nEdges,
    const unsigned int* __restrict__ hist, unsigned int* __restrict__ gpos,
    int4* __restrict__ recs)
{
    __shared__ unsigned int lh[64], loff[64], lcnt[64], lbase[64], lrun[64];
    const int t = threadIdx.x;
    const int per = (nEdges + SCAT_BLOCKS - 1) / SCAT_BLOCKS;
    const int e0 = blockIdx.x * per;
    const int e1 = min(nEdges, e0 + per);

    if (t < 64) { lh[t] = hist[t]; lcnt[t] = 0; lrun[t] = 0; }
    __syncthreads();
    if (t < 64) {                      // exclusive scan of 64 class sizes
        unsigned int o = 0;
        for (int k = 0; k < t; ++k) o += lh[k];
        loff[t] = o;
    }
    // pass 1: count this block's edges per class
    for (int e = e0 + t; e < e1; e += 256) {
        const int s = ei[e], d = ei[nEdges + e];
        atomicAdd(&lcnt[((s & 7) << 3) | (d & 7)], 1u);
    }
    __syncthreads();
    if (t < 64) {                      // reserve contiguous range per class
        const unsigned int c = lcnt[t];
        lbase[t] = loff[t] + (c ? atomicAdd(&gpos[t], c) : 0u);
    }
    __syncthreads();
    // pass 2: place records (ei re-read is L2-hot)
    for (int e = e0 + t; e < e1; e += 256) {
        const int s = ei[e], d = ei[nEdges + e];
        const int cl = ((s & 7) << 3) | (d & 7);
        const unsigned int p = lbase[cl] + atomicAdd(&lrun[cl], 1u);
        recs[p] = make_int4(s, d, e, 0);
    }
}

// ---------------- compute: class (i=blockIdx%8 -> XCD i, j walked in order) -
__global__ __launch_bounds__(256) void edge_mlp_sorted(
    const int4* __restrict__ recs, const unsigned int* __restrict__ AB,
    const unsigned int* __restrict__ hist,
    const float* __restrict__ W2, const float* __restrict__ b2,
    float* __restrict__ out, int nEdges)
{
    __shared__ unsigned int lh[64], loff[64];
    const int t = threadIdx.x;
    if (t < 64) lh[t] = hist[t];
    __syncthreads();
    if (t < 64) {
        unsigned int o = 0;
        for (int k = 0; k < t; ++k) o += lh[k];
        loff[t] = o;
    }
    __syncthreads();

    const int lane = t & 63;
    const int sub  = lane & 7;
    const int grp  = lane >> 3;
    const int wv   = t >> 6;
    const int i    = blockIdx.x & 7;          // XCD pin (blockIdx%8 round-robin)
    const int r    = blockIdx.x >> 3;         // slice 0..255 within XCD

    float w2v[8];
#pragma unroll
    for (int j = 0; j < 8; ++j) w2v[j] = W2[sub * 8 + j];
    const float b2s = b2[0];

    for (int j = 0; j < 8; ++j) {             // B-shard rotates; A-shard stays
        const int c = (i << 3) | j;
        const unsigned int off = loff[c], sz = lh[c];
        const unsigned int chunk = (sz + 255) >> 8;
        const unsigned int s0 = off + r * chunk;
        const unsigned int s1 = min(off + sz, s0 + chunk);
        const unsigned int wc = (chunk + 3) >> 2;
        const unsigned int t0 = s0 + wv * wc;
        const unsigned int t1 = min(s1, t0 + wc);

        for (unsigned int e = t0 + grp; e < t1; e += 8) {
            const int4 rec = recs[e];         // 8 lanes same addr -> broadcast
            const uint4 ua = *reinterpret_cast<const uint4*>(
                AB + (size_t)rec.x * 64 + sub * 4);
            const uint4 ub = *reinterpret_cast<const uint4*>(
                AB + (size_t)rec.y * 64 + 32 + sub * 4);
            const float p = edge_dot(ua, ub, w2v);
            if (sub == 7) out[rec.z] = p + b2s;
        }
    }
}

extern "C" void kernel_launch(void* const* d_in, const int* in_sizes, int n_in,
                              void* d_out, int out_size, void* d_ws, size_t ws_size,
                              hipStream_t stream) {
    const float* emb = (const float*)d_in[0];
    const int*   ei  = (const int*)d_in[1];
    const float* W1  = (const float*)d_in[2];
    const float* b1  = (const float*)d_in[3];
    const float* W2  = (const float*)d_in[4];
    const float* b2  = (const float*)d_in[5];
    float* out = (float*)d_out;

    const int nNodes = in_sizes[0] / 64;   // 50000
    const int nEdges = in_sizes[1] / 2;    // 800000

    // ws layout
    char* ws = (char*)d_ws;
    unsigned short* AB   = (unsigned short*)ws;                    // 12.8 MB
    int4*           recs = (int4*)(ws + (16u << 20));              // 12.8 MB
    unsigned int*   hist = (unsigned int*)(ws + (32u << 20));      // 256 B
    unsigned int*   gpos = hist + 64;                              // 256 B

    hipMemsetAsync(hist, 0, 2 * 64 * sizeof(unsigned int), stream);

    pre_and_hist<<<PRE_BLOCKS + HIST_BLOCKS, 256, 0, stream>>>(
        emb, W1, b1, AB, nNodes, ei, nEdges, hist);

    edge_scatter<<<SCAT_BLOCKS, 256, 0, stream>>>(ei, nEdges, hist, gpos, recs);

    edge_mlp_sorted<<<MLP_BLOCKS, 256, 0, stream>>>(
        recs, (const unsigned int*)AB, hist, W2, b2, out, nEdges);
}

// Round 8
// 132.362 us; speedup vs baseline: 1.1214x; 1.1214x over previous
//
#include <hip/hip_runtime.h>
#include <hip/hip_bf16.h>

// PGExplainer edge-MLP:
//   logits[e] = relu(concat(emb[src], emb[dst]) @ W1 + b1) @ W2 + b2
// Restructured: A[n] = emb[n] @ W1[:64] + b1 ; B[n] = emb[n] @ W1[64:]
//   logits[e] = relu(A[src]+B[dst]) . W2 + b2
// AB[n*128 + j] bf16 (j<64 = A, j>=64 = B) in d_ws.
//
// R8 = MEASUREMENT ROUND. Exact R3/R4 kernels (best measured: 102.7us), but
// pre's tile loop runs x3 and edge's loop runs x2 inside the kernel
// (idempotent rewrites; graph-safe). Purpose: edge x2 (~56-84us) exceeds the
// ~46us fill cutoff and surfaces in rocprof top-5 with its own counters,
// resolving the pre/edge split that rounds 5 and 7 guessed wrong about.
//   edge_cold = edge_row / 2 ;  pre3x = dur - 46.8 - edge_row.

#define PRE_REPS  3
#define EDGE_REPS 2

typedef __attribute__((ext_vector_type(8))) short bf16x8;
typedef __attribute__((ext_vector_type(4))) float f32x4;

__device__ __forceinline__ unsigned short f2bf(float f) {
    union { float f; unsigned int i; } v;
    v.f = f;
    unsigned int r = v.i + 0x7fffu + ((v.i >> 16) & 1u);  // RNE
    return (unsigned short)(r >> 16);
}

template <int N>
__device__ __forceinline__ float dpp_shr(float x) {
    return __int_as_float(__builtin_amdgcn_update_dpp(
        0, __float_as_int(x), 0x110 | N, 0xf, 0xf, true));
}

// MFMA GEMM: AB[50000 x 128] = E[50000 x 64] @ Wbig[64 x 128] (+ b1 cols<64)
// Frag layouts (mfma_f32_16x16x32_bf16):
//   A: row=lane&15, k=(lane>>4)*8+i ; B: col=lane&15, same k
//   D: col=lane&15, row=(lane>>4)*4+reg   [verified m89]
__global__ __launch_bounds__(256) void precompute_ab(
    const float* __restrict__ emb, const float* __restrict__ W1,
    const float* __restrict__ b1, unsigned short* __restrict__ AB,
    int nNodes, int totalWaves)
{
    const int lane = threadIdx.x & 63;
    const int waveId = blockIdx.x * (blockDim.x >> 6) + (threadIdx.x >> 6);
    const int c  = lane & 15;   // col (B/D) / row (A) selector
    const int kb = lane >> 4;   // k-block 0..3

    bf16x8 wfrag[8][2];
    float bias[8];
#pragma unroll
    for (int nt = 0; nt < 8; ++nt) {
        const int jp = nt * 16 + c;                       // output col 0..127
        const float* wcol = (jp < 64) ? (W1 + jp) : (W1 + 64 * 64 + (jp - 64));
        bias[nt] = (jp < 64) ? b1[jp] : 0.f;
#pragma unroll
        for (int kk = 0; kk < 2; ++kk)
#pragma unroll
            for (int i = 0; i < 8; ++i) {
                const int k = kk * 32 + kb * 8 + i;
                wfrag[nt][kk][i] = (short)f2bf(wcol[(size_t)k * 64]);
            }
    }

    for (int rep = 0; rep < PRE_REPS; ++rep) {
        for (int n0 = waveId * 16; n0 < nNodes; n0 += totalWaves * 16) {
            const int arow = n0 + c;
            const float* erow = emb + (size_t)((arow < nNodes) ? arow : (nNodes - 1)) * 64 + kb * 8;
            bf16x8 afrag[2];
#pragma unroll
            for (int kk = 0; kk < 2; ++kk) {
                const float4 f0 = *reinterpret_cast<const float4*>(erow + kk * 32);
                const float4 f1 = *reinterpret_cast<const float4*>(erow + kk * 32 + 4);
                afrag[kk][0] = (short)f2bf(f0.x); afrag[kk][1] = (short)f2bf(f0.y);
                afrag[kk][2] = (short)f2bf(f0.z); afrag[kk][3] = (short)f2bf(f0.w);
                afrag[kk][4] = (short)f2bf(f1.x); afrag[kk][5] = (short)f2bf(f1.y);
                afrag[kk][6] = (short)f2bf(f1.z); afrag[kk][7] = (short)f2bf(f1.w);
            }

            f32x4 acc[8];
#pragma unroll
            for (int nt = 0; nt < 8; ++nt) {
                acc[nt][0] = bias[nt]; acc[nt][1] = bias[nt];
                acc[nt][2] = bias[nt]; acc[nt][3] = bias[nt];
            }
#pragma unroll
            for (int kk = 0; kk < 2; ++kk)
#pragma unroll
                for (int nt = 0; nt < 8; ++nt)
                    acc[nt] = __builtin_amdgcn_mfma_f32_16x16x32_bf16(
                        afrag[kk], wfrag[nt][kk], acc[nt], 0, 0, 0);

            if (n0 + 16 <= nNodes) {
#pragma unroll
                for (int nt = 0; nt < 8; ++nt) {
                    const int jp = nt * 16 + c;
#pragma unroll
                    for (int r = 0; r < 4; ++r)
                        AB[(size_t)(n0 + kb * 4 + r) * 128 + jp] = f2bf(acc[nt][r]);
                }
            } else {
#pragma unroll
                for (int nt = 0; nt < 8; ++nt) {
                    const int jp = nt * 16 + c;
#pragma unroll
                    for (int r = 0; r < 4; ++r) {
                        const int node = n0 + kb * 4 + r;
                        if (node < nNodes) AB[(size_t)node * 128 + jp] = f2bf(acc[nt][r]);
                    }
                }
            }
        }
    }
}

// 8 lanes/edge, 8 edges/wave, unroll 8 (16 uint4 gathers in flight).
// Each lane: 8 hidden units via one uint4 per operand; 8-lane groups read
// 128B contiguous segments. Reduce: 3 DPP row_shr adds -> sub==7.
__global__ __launch_bounds__(256) void edge_mlp(
    const int* __restrict__ ei, const unsigned int* __restrict__ AB,
    const float* __restrict__ W2, const float* __restrict__ b2,
    float* __restrict__ out, int nEdges, int totalWaves)
{
    const int lane = threadIdx.x & 63;
    const int sub  = lane & 7;
    const int grp  = lane >> 3;
    const int waveId = blockIdx.x * (blockDim.x >> 6) + (threadIdx.x >> 6);

    float w2v[8];
#pragma unroll
    for (int j = 0; j < 8; ++j) w2v[j] = W2[sub * 8 + j];
    const float b2s = b2[0];
    const int stride = totalWaves * 8;

    for (int rep = 0; rep < EDGE_REPS; ++rep) {
#pragma unroll 8
        for (int base = waveId * 8; base < nEdges; base += stride) {
            const int e = base + grp;
            const bool valid = (e < nEdges);
            const int ec = valid ? e : 0;

            const int src = ei[ec];
            const int dst = ei[nEdges + ec];

            const uint4 ua = *reinterpret_cast<const uint4*>(AB + (size_t)src * 64 + sub * 4);
            const uint4 ub = *reinterpret_cast<const uint4*>(AB + (size_t)dst * 64 + 32 + sub * 4);

            float p = 0.f;
            const unsigned int au[4] = {ua.x, ua.y, ua.z, ua.w};
            const unsigned int bu[4] = {ub.x, ub.y, ub.z, ub.w};
#pragma unroll
            for (int i = 0; i < 4; ++i) {
                const float alo = __int_as_float((int)(au[i] << 16));
                const float ahi = __int_as_float((int)(au[i] & 0xffff0000u));
                const float blo = __int_as_float((int)(bu[i] << 16));
                const float bhi = __int_as_float((int)(bu[i] & 0xffff0000u));
                const float h0 = fmaxf(alo + blo, 0.f);
                const float h1 = fmaxf(ahi + bhi, 0.f);
                p = fmaf(h0, w2v[2 * i], p);
                p = fmaf(h1, w2v[2 * i + 1], p);
            }

            p += dpp_shr<1>(p);
            p += dpp_shr<2>(p);
            p += dpp_shr<4>(p);

            if (valid && sub == 7) out[e] = p + b2s;
        }
    }
}

extern "C" void kernel_launch(void* const* d_in, const int* in_sizes, int n_in,
                              void* d_out, int out_size, void* d_ws, size_t ws_size,
                              hipStream_t stream) {
    const float* emb = (const float*)d_in[0];
    const int*   ei  = (const int*)d_in[1];
    const float* W1  = (const float*)d_in[2];
    const float* b1  = (const float*)d_in[3];
    const float* W2  = (const float*)d_in[4];
    const float* b2  = (const float*)d_in[5];
    float* out = (float*)d_out;
    unsigned short* AB = (unsigned short*)d_ws;   // nNodes*128 bf16 = 12.8 MB

    const int nNodes = in_sizes[0] / 64;   // 50000
    const int nEdges = in_sizes[1] / 2;    // 800000

    {
        // identical to R3: 256 blocks = 1024 waves, 16 nodes/wave/iter
        const int blocks = 256;
        precompute_ab<<<blocks, 256, 0, stream>>>(emb, W1, b1, AB, nNodes, blocks * 4);
    }
    {
        // identical to R3: 2048 blocks = 8192 waves, 8 edges/iter, unroll 8
        const int blocks = 2048;
        edge_mlp<<<blocks, 256, 0, stream>>>(ei, (const unsigned int*)AB, W2, b2,
                                             out, nEdges, blocks * 4);
    }
}